// Round 10
// baseline (312.808 us; speedup 1.0000x reference)
//
#include <hip/hip_runtime.h>
#include <hip/hip_bf16.h>
#include <math.h>

#define SEQ_LEN 128
#define BATCH   32
#define T       32
#define TT      (T*T)     // 1024
#define TTT     (T*T*T)   // 32768
#define START   30
#define END     31

#define LOG2E   1.44269504088896f
#define OFF4    5.77078016355587f   // 4 * log2(e)

typedef unsigned long long u64;

__device__ __forceinline__ u64 pt_pack(int tag, float v) {
    union { float f; unsigned int u; } c; c.f = v;
    return ((u64)(unsigned int)tag << 32) | (u64)c.u;
}
__device__ __forceinline__ float pt_val(u64 w) {
    union { unsigned int u; float f; } c; c.u = (unsigned int)w; return c.f;
}
__device__ __forceinline__ int pt_tag(u64 w) { return (int)(w >> 32); }

__device__ __forceinline__ u64 ald64(const u64* p) {
    return __hip_atomic_load(p, __ATOMIC_RELAXED, __HIP_MEMORY_SCOPE_AGENT);
}
__device__ __forceinline__ void ast64(u64* p, u64 v) {
    __hip_atomic_store(p, v, __ATOMIC_RELAXED, __HIP_MEMORY_SCOPE_AGENT);
}

#define WAITV0() do { asm volatile("s_waitcnt vmcnt(0)" ::: "memory");  \
                      __builtin_amdgcn_sched_barrier(0); } while (0)

#define BLOCK_SYNC() do {                                   \
    asm volatile("s_waitcnt lgkmcnt(0)" ::: "memory");      \
    __builtin_amdgcn_sched_barrier(0);                      \
    __builtin_amdgcn_s_barrier();                           \
    __builtin_amdgcn_sched_barrier(0);                      \
} while (0)

// ---------------------------------------------------------------------------
// Kernel 1: tg_energy gather. ws[0..15] <- per-block partial sums.
// ---------------------------------------------------------------------------
__global__ __launch_bounds__(256) void tg_kernel(const float* __restrict__ scores,
                                                 const int*   __restrict__ target,
                                                 const int*   __restrict__ mask,
                                                 float*       __restrict__ ws) {
    int idx = blockIdx.x * 256 + threadIdx.x;
    float v = 0.0f;
    if (mask[idx] != 0) v = scores[(size_t)idx * TTT + target[idx]];
    #pragma unroll
    for (int off = 32; off > 0; off >>= 1) v += __shfl_down(v, off, 64);
    __shared__ float partial[4];
    int wave = threadIdx.x >> 6, lane = threadIdx.x & 63;
    if (lane == 0) partial[wave] = v;
    __syncthreads();
    if (threadIdx.x == 0)
        ws[blockIdx.x] = partial[0] + partial[1] + partial[2] + partial[3];
}

// ---------------------------------------------------------------------------
// Kernel 2: init, 3 parity buffers (replay-safe full overwrite).
// ptF[b] (3x1024 u64): parity1 = Q_1 tag 1, layout [j*32+i]; parity0/2 = 0.
// ptB[b]: parity2 = R_127 tag 128 (indicator), layout [j*32+k]; parity0/1 = 0.
// ---------------------------------------------------------------------------
__global__ __launch_bounds__(256) void init_reg(const float* __restrict__ scores,
                                                u64* __restrict__ ptF,
                                                u64* __restrict__ ptB) {
    const int blk = blockIdx.x, tid = threadIdx.x;
    if (blk < BATCH) {
        const int b = blk;
        u64* pt = ptF + (size_t)b * 3072;
        #pragma unroll
        for (int q = 0; q < 4; ++q) {
            int e = q * 256 + tid;           // e = j*32 + i
            int i = e & 31, j = e >> 5;
            float p1 = scores[(size_t)(0*BATCH + b)*TTT + START*TT + START*T + i];
            float s1 = scores[(size_t)(1*BATCH + b)*TTT + START*TT + i*T + j];
            pt[1024 + e] = pt_pack(1, __expf(p1 + s1));
            pt[e]        = 0ULL;
            pt[2048 + e] = 0ULL;
        }
    } else {
        const int b = blk - BATCH;
        u64* pt = ptB + (size_t)b * 3072;
        #pragma unroll
        for (int q = 0; q < 4; ++q) {
            int e = q * 256 + tid;           // e = j*32 + k
            pt[2048 + e] = pt_pack(128, (e == END*T + END) ? 1.0f : 0.0f);
            pt[e]        = 0ULL;
            pt[1024 + e] = 0ULL;
        }
    }
}

// ---------------------------------------------------------------------------
// Kernel 3: register-direct distributed fwd/bwd scan. 512 blocks x 512 thr,
// 2 blocks/CU co-resident. g=bid&7, chain=bid>>3, b=chain&31, dirB=chain>=32.
// 3 parity buffers (parity = t%3): overwrite distance 3 > certification
// depth 2 (each quad's publish certifies a full-column read; all-to-all
// mixing closes over all 1024 owners in 2 steps) => deadlock-free, no
// cross-block fences, no intra-block exchange barriers.
//  FWD t=2..64:  quad (jcol=4g+jj, k), s4 lanes: poll S[i,jcol] i in
//    [8s4,8s4+8) (tag t-1, parity (t-1)%3) -> regs; E from LDS tile
//    (double-buffered, 1 barrier/step AFTER publish); publish Q_t[jcol,k]
//    at [k*32+jcol] tag t parity t%3.
//  BWD t=127..65: octet (jb=4g+jjB, i0/i0+16), k4 lanes: poll R[jb,k]
//    4 words -> regs; E in registers (contiguous loads); publish
//    R_{t-1}[i,jb] at [i*32+jb] tag t parity t%3. Zero barriers.
// Masked steps: poll column anyway (certification), republish cached regs
// after vmcnt(0).
// ---------------------------------------------------------------------------
__global__ __launch_bounds__(512, 4) void scan_reg(const float* __restrict__ scores,
                                                   const int*   __restrict__ maskI,
                                                   u64*         __restrict__ ptF,
                                                   u64*         __restrict__ ptB) {
    const int bid   = blockIdx.x;
    const int g     = bid & 7;
    const int chain = bid >> 3;
    const int b     = chain & 31;
    const bool dirB = (chain >> 5) != 0;
    const int tid   = threadIdx.x;
    const int lane  = tid & 63;

    // mask bitfields (wave-uniform registers; no LDS in the loop)
    const u64 mlo = __ballot(maskI[lane * BATCH + b] != 0);
    const u64 mhi = __ballot(maskI[(64 + lane) * BATCH + b] != 0);

    u64* const pt = (dirB ? ptB : ptF) + (size_t)b * 3072;
    auto sb     = [&](int t) { return scores + ((size_t)t * BATCH + b) * TTT; };
    auto act_of = [&](int t) { return (((t < 64) ? (mlo >> t) : (mhi >> (t - 64))) & 1ULL) != 0ULL; };

    const int i0 = tid >> 5;                 // 0..15
    const int f  = tid & 31;
    const size_t offA = (size_t)i0 * TT + g * 128 + f * 4;

    if (!dirB) {
        // ------------------------------ FORWARD ------------------------------
        __shared__ __align__(16) float sm[2][128 * 33];
        const int oF = tid >> 2, s4 = tid & 3;
        const int jj = oF >> 5, k = oF & 31;
        const int jcol = 4 * g + jj;
        const int ownW = k * 32 + jcol;

        float lastval = 0.f;
        if (s4 == 0) lastval = pt_val(ald64(pt + 1024 + ownW));   // init parity1

        float4 A0, A1, B0, B1;
        auto issue = [&](float4& X, float4& Y, int t) {
            const float* p = sb(t) + offA;
            X = *(const float4*)p; Y = *(const float4*)(p + 16 * TT);
        };
        auto scat = [&](int buf, const float4& X, const float4& Y) {
            #pragma unroll
            for (int q = 0; q < 4; ++q) {
                sm[buf][(f*4 + q)*33 + i0]      = (&X.x)[q];
                sm[buf][(f*4 + q)*33 + i0 + 16] = (&Y.x)[q];
            }
        };
        auto stepF = [&](int t, int buf) {
            const bool act = act_of(t);
            const int tagw = t - 1;
            const u64* src = pt + (size_t)((t - 1) % 3) * 1024 + jcol * 32 + 8 * s4;
            u64* dst = pt + (size_t)(t % 3) * 1024;
            u64 w0, w1, w2, w3, w4, w5, w6, w7;
            bool d0=false,d1=false,d2=false,d3=false,d4=false,d5=false,d6=false,d7=false;
            for (;;) {
                if (!d0) { w0 = ald64(src + 0); d0 = pt_tag(w0) == tagw; }
                if (!d1) { w1 = ald64(src + 1); d1 = pt_tag(w1) == tagw; }
                if (!d2) { w2 = ald64(src + 2); d2 = pt_tag(w2) == tagw; }
                if (!d3) { w3 = ald64(src + 3); d3 = pt_tag(w3) == tagw; }
                if (!d4) { w4 = ald64(src + 4); d4 = pt_tag(w4) == tagw; }
                if (!d5) { w5 = ald64(src + 5); d5 = pt_tag(w5) == tagw; }
                if (!d6) { w6 = ald64(src + 6); d6 = pt_tag(w6) == tagw; }
                if (!d7) { w7 = ald64(src + 7); d7 = pt_tag(w7) == tagw; }
                if (__all(d0 && d1 && d2 && d3 && d4 && d5 && d6 && d7)) break;
            }
            if (act) {
                const float* row = &sm[buf][oF * 33 + 8 * s4];
                float acc = 0.f;
                acc = fmaf(exp2f(fmaf(row[0], LOG2E, -OFF4)), pt_val(w0), acc);
                acc = fmaf(exp2f(fmaf(row[1], LOG2E, -OFF4)), pt_val(w1), acc);
                acc = fmaf(exp2f(fmaf(row[2], LOG2E, -OFF4)), pt_val(w2), acc);
                acc = fmaf(exp2f(fmaf(row[3], LOG2E, -OFF4)), pt_val(w3), acc);
                acc = fmaf(exp2f(fmaf(row[4], LOG2E, -OFF4)), pt_val(w4), acc);
                acc = fmaf(exp2f(fmaf(row[5], LOG2E, -OFF4)), pt_val(w5), acc);
                acc = fmaf(exp2f(fmaf(row[6], LOG2E, -OFF4)), pt_val(w6), acc);
                acc = fmaf(exp2f(fmaf(row[7], LOG2E, -OFF4)), pt_val(w7), acc);
                acc += __shfl_xor(acc, 1, 64);
                acc += __shfl_xor(acc, 2, 64);
                if (s4 == 0) { lastval = acc; ast64(dst + ownW, pt_pack(t, acc)); }
            } else {
                WAITV0();   // order republish after certification poll
                if (s4 == 0) ast64(dst + ownW, pt_pack(t, lastval));
            }
        };

        issue(A0, A1, 2); issue(B0, B1, 3);
        scat(0, A0, A1);
        BLOCK_SYNC();
        for (int t = 2; t <= 64; t += 2) {
            if (t + 2 <= 64) issue(A0, A1, t + 2);
            stepF(t, 0);
            if (t + 1 > 64) break;
            scat(1, B0, B1);
            BLOCK_SYNC();
            if (t + 3 <= 64) issue(B0, B1, t + 3);
            stepF(t + 1, 1);
            scat(0, A0, A1);
            BLOCK_SYNC();
        }
    } else {
        // ------------------------------ BACKWARD ------------------------------
        const int jjB = f >> 3, k4 = f & 7;
        const int jb = 4 * g + jjB;
        const int ownW0 = i0 * 32 + jb, ownW1 = (i0 + 16) * 32 + jb;

        float last0 = 0.f, last1 = 0.f;
        if (k4 == 0) {
            last0 = pt_val(ald64(pt + 2048 + ownW0));   // init parity2
            last1 = pt_val(ald64(pt + 2048 + ownW1));
        }

        float4 A0, A1, B0, B1;
        auto issue = [&](float4& X, float4& Y, int t) {
            const float* p = sb(t) + offA;
            X = *(const float4*)p; Y = *(const float4*)(p + 16 * TT);
        };
        auto stepB = [&](int t, const float4& X, const float4& Y) {
            const bool act = act_of(t);
            const int tagw = t + 1;
            const u64* src = pt + (size_t)((t + 1) % 3) * 1024 + jb * 32 + 4 * k4;
            u64* dst = pt + (size_t)(t % 3) * 1024;
            u64 w0, w1, w2, w3;
            bool d0=false,d1=false,d2=false,d3=false;
            for (;;) {
                if (!d0) { w0 = ald64(src + 0); d0 = pt_tag(w0) == tagw; }
                if (!d1) { w1 = ald64(src + 1); d1 = pt_tag(w1) == tagw; }
                if (!d2) { w2 = ald64(src + 2); d2 = pt_tag(w2) == tagw; }
                if (!d3) { w3 = ald64(src + 3); d3 = pt_tag(w3) == tagw; }
                if (__all(d0 && d1 && d2 && d3)) break;
            }
            if (act) {
                const float r0 = pt_val(w0), r1 = pt_val(w1),
                            r2 = pt_val(w2), r3 = pt_val(w3);
                float a0 = 0.f, a1 = 0.f;
                a0 = fmaf(exp2f(fmaf(X.x, LOG2E, -OFF4)), r0, a0);
                a0 = fmaf(exp2f(fmaf(X.y, LOG2E, -OFF4)), r1, a0);
                a0 = fmaf(exp2f(fmaf(X.z, LOG2E, -OFF4)), r2, a0);
                a0 = fmaf(exp2f(fmaf(X.w, LOG2E, -OFF4)), r3, a0);
                a1 = fmaf(exp2f(fmaf(Y.x, LOG2E, -OFF4)), r0, a1);
                a1 = fmaf(exp2f(fmaf(Y.y, LOG2E, -OFF4)), r1, a1);
                a1 = fmaf(exp2f(fmaf(Y.z, LOG2E, -OFF4)), r2, a1);
                a1 = fmaf(exp2f(fmaf(Y.w, LOG2E, -OFF4)), r3, a1);
                a0 += __shfl_xor(a0, 1, 64); a0 += __shfl_xor(a0, 2, 64); a0 += __shfl_xor(a0, 4, 64);
                a1 += __shfl_xor(a1, 1, 64); a1 += __shfl_xor(a1, 2, 64); a1 += __shfl_xor(a1, 4, 64);
                if (k4 == 0) {
                    last0 = a0; last1 = a1;
                    ast64(dst + ownW0, pt_pack(t, a0));
                    ast64(dst + ownW1, pt_pack(t, a1));
                }
            } else {
                WAITV0();
                if (k4 == 0) {
                    ast64(dst + ownW0, pt_pack(t, last0));
                    ast64(dst + ownW1, pt_pack(t, last1));
                }
            }
        };

        issue(A0, A1, 127); issue(B0, B1, 126);
        for (int t = 127; t >= 65; t -= 2) {
            stepB(t, A0, A1);
            if (t - 2 >= 65) issue(A0, A1, t - 2);
            if (t - 1 < 65) break;
            stepB(t - 1, B0, B1);
            if (t - 3 >= 65) issue(B0, B1, t - 3);
        }
    }
}

// ---------------------------------------------------------------------------
// Kernel 4: finalize. Q_64 = ptF parity1 (tag 64), layout [k*32+j];
// R_64 = ptB parity2 (tag 65), layout [i*32+j].
// z_b = 4*cnt_b + log( sum_{j,k} Q_64[j,k] * R_64[j,k] ).
// ---------------------------------------------------------------------------
__global__ __launch_bounds__(1024) void finalize_reg(const float* __restrict__ ws,
                                                     const u64*  __restrict__ ptF,
                                                     const u64*  __restrict__ ptB,
                                                     const int*  __restrict__ mask,
                                                     float*      __restrict__ out) {
    __shared__ float zs[32];
    const int w = threadIdx.x >> 6, lane = threadIdx.x & 63;
    for (int rep = 0; rep < 2; ++rep) {
        const int b = w + rep * 16;
        const u64* qf = ptF + (size_t)b * 3072 + 1024;
        const u64* rb = ptB + (size_t)b * 3072 + 2048;
        float dot = 0.f;
        #pragma unroll
        for (int e = 0; e < 16; ++e) {
            const int x = lane + 64 * e;                 // x = k*32 + j
            dot += pt_val(qf[x]) * pt_val(rb[(x & 31) * 32 + (x >> 5)]);
        }
        float cnt = 0.f;
        {
            int t = 2 + lane;
            if (t < SEQ_LEN) cnt += (mask[t*BATCH + b] != 0) ? 1.f : 0.f;
            t += 64;
            if (t < SEQ_LEN) cnt += (mask[t*BATCH + b] != 0) ? 1.f : 0.f;
        }
        #pragma unroll
        for (int off = 32; off > 0; off >>= 1) {
            dot += __shfl_xor(dot, off, 64);
            cnt += __shfl_xor(cnt, off, 64);
        }
        if (lane == 0) zs[b] = 4.0f * cnt + logf(dot);
    }
    __syncthreads();
    if (threadIdx.x == 0) {
        float tg = 0.f, z = 0.f;
        #pragma unroll
        for (int i = 0; i < 16; ++i) tg += ws[i];
        #pragma unroll
        for (int i = 0; i < 32; ++i) z += zs[i];
        out[0] = (z - tg) / (float)BATCH;
    }
}

// ---------------------------------------------------------------------------
// Fallback (small ws): round-5 single-block-per-batch scan.
// ---------------------------------------------------------------------------
__global__ __launch_bounds__(1024) void scan_fast(const float* __restrict__ scores,
                                                  const int*   __restrict__ maskI,
                                                  float*       __restrict__ ws) {
    const int b    = blockIdx.x;
    const int tid  = threadIdx.x;
    const int w    = tid >> 6;
    const int lane = tid & 63;
    const int h    = lane >> 4;
    const int jp   = (lane >> 3) & 1;
    const int k4   = lane & 7;
    const int j    = w * 2 + jp;

    __shared__ float Q[2][TT];
    __shared__ int   lmask[SEQ_LEN];
    if (tid < SEQ_LEN) lmask[tid] = maskI[tid * BATCH + b];
    {
        int x = tid >> 5, y = tid & 31;
        float p1 = scores[(size_t)(0*BATCH + b)*TTT + START*TT + START*T + x];
        float s1 = scores[(size_t)(1*BATCH + b)*TTT + START*TT + x*T + y];
        Q[1][x*T + y] = __expf(p1 + s1);
    }
    __syncthreads();
    const int loff = h*8*TT + j*T + k4*4;
    float4 SA[8], SB[8];
    auto issue = [&](float4 (&S)[8], int t) {
        const float* p = scores + ((size_t)t*BATCH + b)*TTT + loff;
        #pragma unroll
        for (int m = 0; m < 8; ++m) S[m] = *(const float4*)(p + m*TT);
    };
    auto process = [&](float4 (&S)[8], int t) {
        const float* qc = Q[(t-1) & 1];
        float*       qn = Q[t & 1];
        #pragma unroll
        for (int m = 0; m < 8; ++m) {
            S[m].x = exp2f(fmaf(S[m].x, LOG2E, -OFF4));
            S[m].y = exp2f(fmaf(S[m].y, LOG2E, -OFF4));
            S[m].z = exp2f(fmaf(S[m].z, LOG2E, -OFF4));
            S[m].w = exp2f(fmaf(S[m].w, LOG2E, -OFF4));
        }
        float4 acc = make_float4(0.f, 0.f, 0.f, 0.f);
        #pragma unroll
        for (int m = 0; m < 8; ++m) {
            float q = qc[(h*8 + m)*T + j];
            acc.x = fmaf(S[m].x, q, acc.x);
            acc.y = fmaf(S[m].y, q, acc.y);
            acc.z = fmaf(S[m].z, q, acc.z);
            acc.w = fmaf(S[m].w, q, acc.w);
        }
        acc.x += __shfl_xor(acc.x, 16, 64); acc.y += __shfl_xor(acc.y, 16, 64);
        acc.z += __shfl_xor(acc.z, 16, 64); acc.w += __shfl_xor(acc.w, 16, 64);
        acc.x += __shfl_xor(acc.x, 32, 64); acc.y += __shfl_xor(acc.y, 32, 64);
        acc.z += __shfl_xor(acc.z, 32, 64); acc.w += __shfl_xor(acc.w, 32, 64);
        if (lane < 16) {
            if (lmask[t] != 0) *(float4*)&qn[j*T + k4*4] = acc;
            else               *(float4*)&qn[j*T + k4*4] = *(const float4*)&qc[j*T + k4*4];
        }
        BLOCK_SYNC();
    };
    issue(SA, 2);
    for (int t = 2; t < SEQ_LEN; t += 2) {
        issue(SB, t + 1);
        process(SA, t);
        if (t + 2 < SEQ_LEN) issue(SA, t + 2);
        process(SB, t + 1);
    }
    if (tid == 0) {
        int cnt = 0;
        for (int t = 2; t < SEQ_LEN; ++t) cnt += (lmask[t] != 0);
        ws[16 + b] = 4.0f * (float)cnt + logf(Q[1][END*T + END]);
    }
}

__global__ void finalize_simple(const float* __restrict__ ws, float* __restrict__ out) {
    if (threadIdx.x == 0) {
        float tg = 0.f, z = 0.f;
        #pragma unroll
        for (int i = 0; i < 16; ++i) tg += ws[i];
        #pragma unroll
        for (int i = 0; i < 32; ++i) z += ws[16 + i];
        out[0] = (z - tg) / (float)BATCH;
    }
}

extern "C" void kernel_launch(void* const* d_in, const int* in_sizes, int n_in,
                              void* d_out, int out_size, void* d_ws, size_t ws_size,
                              hipStream_t stream) {
    const float* scores = (const float*)d_in[0];
    const int*   target = (const int*)d_in[1];
    const int*   mask   = (const int*)d_in[2];
    float* out = (float*)d_out;
    float* ws  = (float*)d_ws;
    u64*   ptF = (u64*)((char*)d_ws + 1024);
    u64*   ptB = ptF + (size_t)BATCH * 3072;
    const size_t need = 1024 + (size_t)2 * BATCH * 3072 * sizeof(u64);   // ~1.58 MB

    tg_kernel<<<16, 256, 0, stream>>>(scores, target, mask, ws);
    if (ws_size >= need) {
        init_reg<<<2*BATCH, 256, 0, stream>>>(scores, ptF, ptB);
        scan_reg<<<512, 512, 0, stream>>>(scores, mask, ptF, ptB);
        finalize_reg<<<1, 1024, 0, stream>>>(ws, ptF, ptB, mask, out);
    } else {
        scan_fast<<<BATCH, 1024, 0, stream>>>(scores, mask, ws);
        finalize_simple<<<1, 64, 0, stream>>>(ws, out);
    }
}

// Round 11
// 185.605 us; speedup vs baseline: 1.6853x; 1.6853x over previous
//
#include <hip/hip_runtime.h>
#include <hip/hip_bf16.h>
#include <math.h>

#define SEQ_LEN 128
#define BATCH   32
#define T       32
#define TT      (T*T)     // 1024
#define TTT     (T*T*T)   // 32768
#define START   30
#define END     31

#define LOG2E   1.44269504088896f
#define OFF4    5.77078016355587f   // 4 * log2(e)

typedef unsigned long long u64;

__device__ __forceinline__ u64 pt_pack(int tag, float v) {
    union { float f; unsigned int u; } c; c.f = v;
    return ((u64)(unsigned int)tag << 32) | (u64)c.u;
}
__device__ __forceinline__ float pt_val(u64 w) {
    union { unsigned int u; float f; } c; c.u = (unsigned int)w; return c.f;
}
__device__ __forceinline__ int pt_tag(u64 w) { return (int)(w >> 32); }

__device__ __forceinline__ u64 ald64(const u64* p) {
    return __hip_atomic_load(p, __ATOMIC_RELAXED, __HIP_MEMORY_SCOPE_AGENT);
}
__device__ __forceinline__ void ast64(u64* p, u64 v) {
    __hip_atomic_store(p, v, __ATOMIC_RELAXED, __HIP_MEMORY_SCOPE_AGENT);
}

// raw barrier: drain LDS ops only; global prefetch/publish stay in flight
#define BLOCK_SYNC() do {                                   \
    asm volatile("s_waitcnt lgkmcnt(0)" ::: "memory");      \
    __builtin_amdgcn_sched_barrier(0);                      \
    __builtin_amdgcn_s_barrier();                           \
    __builtin_amdgcn_sched_barrier(0);                      \
} while (0)

// ---------------------------------------------------------------------------
// Kernel 1: tg_energy gather. ws[0..15] <- per-block partial sums.
// ---------------------------------------------------------------------------
__global__ __launch_bounds__(256) void tg_kernel(const float* __restrict__ scores,
                                                 const int*   __restrict__ target,
                                                 const int*   __restrict__ mask,
                                                 float*       __restrict__ ws) {
    int idx = blockIdx.x * 256 + threadIdx.x;
    float v = 0.0f;
    if (mask[idx] != 0) v = scores[(size_t)idx * TTT + target[idx]];
    #pragma unroll
    for (int off = 32; off > 0; off >>= 1) v += __shfl_down(v, off, 64);
    __shared__ float partial[4];
    int wave = threadIdx.x >> 6, lane = threadIdx.x & 63;
    if (lane == 0) partial[wave] = v;
    __syncthreads();
    if (threadIdx.x == 0)
        ws[blockIdx.x] = partial[0] + partial[1] + partial[2] + partial[3];
}

// ---------------------------------------------------------------------------
// Kernel 2: init tagged buffers (full overwrite each launch: replay-safe).
// ptF[b]: parity1 <- Q_1 (tag 1) at word j*32+i (consumed convention),
//         parity0 <- 0.  ptB[b]: parity0 <- R_127 (tag 128, indicator at
//         word END*32+END), parity1 <- 0.
// ---------------------------------------------------------------------------
__global__ __launch_bounds__(256) void init_dfb(const float* __restrict__ scores,
                                                u64* __restrict__ ptF,
                                                u64* __restrict__ ptB) {
    const int blk = blockIdx.x, tid = threadIdx.x;
    if (blk < BATCH) {
        const int b = blk;
        u64* pt = ptF + (size_t)b * 2048;
        #pragma unroll
        for (int q = 0; q < 4; ++q) {
            int e = q * 256 + tid;           // e = j*32 + i
            int i = e & 31, j = e >> 5;
            float p1 = scores[(size_t)(0*BATCH + b)*TTT + START*TT + START*T + i];
            float s1 = scores[(size_t)(1*BATCH + b)*TTT + START*TT + i*T + j];
            pt[1024 + e] = pt_pack(1, __expf(p1 + s1));
            pt[e]        = 0ULL;
        }
    } else {
        const int b = blk - BATCH;
        u64* pt = ptB + (size_t)b * 2048;
        #pragma unroll
        for (int q = 0; q < 4; ++q) {
            int e = q * 256 + tid;           // e = i*32 + j
            float v = (e == END*T + END) ? 1.0f : 0.0f;
            pt[e]        = pt_pack(128, v);
            pt[1024 + e] = 0ULL;
        }
    }
}

// ---------------------------------------------------------------------------
// Kernel 3: refined distributed fwd/bwd scan. 512 blocks x 512 threads,
// 2 blocks/CU co-resident (launch_bounds(512,4) => <=128 VGPR).
// g=bid&7, chain=bid>>3, b=chain&31, dirB=chain>=32.
// Protocol (r8, proven): per-word tagged u64, relaxed agent atomics, wave0
// polls its block's contiguous 128-word consumed range EVERY step (data +
// overwrite certification); 2 parity buffers; B1 gates all lanes.
// NEW vs r8: owner lanes publish directly after compute (no res relay, no
// B2); fwd tile 4-deep LDS buffered so the scatter runs in the poll shadow;
// pld double-buffered; masked steps publish register-cached values.
// State word convention: word w of a parity holds S consumed-as
// [a=w&31, b=w>>5] (fwd) / [a=w>>5, b=w&31] (bwd); block g's poll range is
// always words [128g, 128g+128) -- contiguous 1 KB.
// ---------------------------------------------------------------------------
__global__ __launch_bounds__(512, 4) void scan_rd(const float* __restrict__ scores,
                                                  const int*   __restrict__ maskI,
                                                  u64*         __restrict__ ptF,
                                                  u64*         __restrict__ ptB) {
    const int bid   = blockIdx.x;
    const int g     = bid & 7;
    const int chain = bid >> 3;
    const int b     = chain & 31;
    const bool dirB = (chain >> 5) != 0;
    const int tid   = threadIdx.x;
    const int lane  = tid & 63;

    // mask as wave-uniform bitfields (no LDS traffic in the loop)
    const u64 mlo = __ballot(maskI[lane * BATCH + b] != 0);
    const u64 mhi = __ballot(maskI[(64 + lane) * BATCH + b] != 0);
    auto act_of = [&](int t) {
        return (((t < 64) ? (mlo >> t) : (mhi >> (t - 64))) & 1ULL) != 0ULL;
    };

    u64* const pt = (dirB ? ptB : ptF) + (size_t)b * 2048;
    const int i0 = tid >> 5;                 // 0..15
    const int f  = tid & 31;
    const size_t offA = (size_t)i0 * TT + g * 128 + f * 4;
    auto sb = [&](int t) { return scores + ((size_t)t * BATCH + b) * TTT; };

    if (!dirB) {
        // ------------------------------ FORWARD ------------------------------
        // steps t=2..64: Q_t[j,k] = sum_i E_t[i,j,k] Q_{t-1}[i,j], j in Jc.
        __shared__ __align__(16) float sm[4][128 * 33];   // tile t -> buf t&3
        __shared__ __align__(16) float pld[2][128];
        const int oF = tid >> 2, s4 = tid & 3;            // output oF=(jj,k)
        const int jj = oF >> 5, k = oF & 31;
        const int jcol = 4 * g + jj;
        const int ownW = k * 32 + jcol;                   // owned state word
        float lastval = pt_val(pt[1024 + ownW]);          // init parity1 value

        float4 X0, X1;
        auto issue = [&](int t) {
            const float* p = sb(t) + offA;
            X0 = *(const float4*)p; X1 = *(const float4*)(p + 16 * TT);
        };
        auto scat = [&](int bf) {
            #pragma unroll
            for (int q = 0; q < 4; ++q) {
                sm[bf][(f*4 + q)*33 + i0]      = (&X0.x)[q];
                sm[bf][(f*4 + q)*33 + i0 + 16] = (&X1.x)[q];
            }
        };

        issue(2); scat(2);
        issue(3); scat(3);
        issue(4);
        __syncthreads();

        for (int t = 2; t <= 64; ++t) {
            const bool act  = act_of(t);
            const int  pbuf = t & 1;
            // scatter tile t+2 into buf (t+2)&3 (safe: its last reads were at
            // step t-2, certified complete by B1(t-1)); then issue tile t+3.
            if (t + 2 <= 64) scat((t + 2) & 3);
            if (t + 3 <= 64) issue(t + 3);
            // wave0: poll consumed range [128g,128g+128), tag t-1
            if (tid < 64) {
                const int tagw = t - 1;
                const u64* src = pt + (size_t)((t - 1) & 1) * 1024 + 128 * g;
                u64 w0, w1; bool d0 = false, d1 = false;
                for (;;) {
                    if (!d0) { w0 = ald64(src + lane);      d0 = pt_tag(w0) == tagw; }
                    if (!d1) { w1 = ald64(src + 64 + lane); d1 = pt_tag(w1) == tagw; }
                    if (__all(d0 && d1)) break;
                }
                pld[pbuf][lane]      = pt_val(w0);
                pld[pbuf][lane + 64] = pt_val(w1);
            }
            BLOCK_SYNC();   // B1: pld + tile buf(t&3) ready; certifies reads
            u64* dst = pt + (size_t)(t & 1) * 1024;
            if (act) {
                const float* row = &sm[t & 3][oF * 33 + 8 * s4];
                const float* pp  = &pld[pbuf][jj * 32 + 8 * s4];
                float acc = 0.f;
                #pragma unroll
                for (int m = 0; m < 8; ++m)
                    acc = fmaf(exp2f(fmaf(row[m], LOG2E, -OFF4)), pp[m], acc);
                acc += __shfl_xor(acc, 1, 64);
                acc += __shfl_xor(acc, 2, 64);
                if (s4 == 0) { lastval = acc; ast64(dst + ownW, pt_pack(t, acc)); }
            } else {
                if (s4 == 0) ast64(dst + ownW, pt_pack(t, lastval));
            }
        }
    } else {
        // ------------------------------ BACKWARD ------------------------------
        // steps t=127..65: R_{t-1}[i,j] = sum_k E_t[i,j,k] R_t[j,k], j in Jc.
        __shared__ __align__(16) float pld[2][128];
        const int jj = f >> 3, k4 = f & 7;
        const int jb = 4 * g + jj;
        const int ownW0 = i0 * 32 + jb, ownW1 = (i0 + 16) * 32 + jb;
        float last0 = pt_val(pt[ownW0]);      // init parity0 values
        float last1 = pt_val(pt[ownW1]);

        float4 A0, A1, B0, B1;
        auto issueR = [&](float4& Y0, float4& Y1, int t) {
            const float* p = sb(t) + offA;
            Y0 = *(const float4*)p; Y1 = *(const float4*)(p + 16 * TT);
        };

        auto stepB = [&](int t, const float4& X0, const float4& X1) {
            const bool act  = act_of(t);
            const int  pbuf = t & 1;
            if (tid < 64) {
                const int tagw = t + 1;
                const u64* src = pt + (size_t)((t + 1) & 1) * 1024 + 128 * g;
                u64 w0, w1; bool d0 = false, d1 = false;
                for (;;) {
                    if (!d0) { w0 = ald64(src + lane);      d0 = pt_tag(w0) == tagw; }
                    if (!d1) { w1 = ald64(src + 64 + lane); d1 = pt_tag(w1) == tagw; }
                    if (__all(d0 && d1)) break;
                }
                pld[pbuf][lane]      = pt_val(w0);
                pld[pbuf][lane + 64] = pt_val(w1);
            }
            BLOCK_SYNC();
            u64* dst = pt + (size_t)(t & 1) * 1024;
            if (act) {
                const float4 Rv = *(const float4*)&pld[pbuf][jj * 32 + 4 * k4];
                float a0, a1;
                a0 = exp2f(fmaf(X0.x, LOG2E, -OFF4)) * Rv.x;
                a0 = fmaf(exp2f(fmaf(X0.y, LOG2E, -OFF4)), Rv.y, a0);
                a0 = fmaf(exp2f(fmaf(X0.z, LOG2E, -OFF4)), Rv.z, a0);
                a0 = fmaf(exp2f(fmaf(X0.w, LOG2E, -OFF4)), Rv.w, a0);
                a1 = exp2f(fmaf(X1.x, LOG2E, -OFF4)) * Rv.x;
                a1 = fmaf(exp2f(fmaf(X1.y, LOG2E, -OFF4)), Rv.y, a1);
                a1 = fmaf(exp2f(fmaf(X1.z, LOG2E, -OFF4)), Rv.z, a1);
                a1 = fmaf(exp2f(fmaf(X1.w, LOG2E, -OFF4)), Rv.w, a1);
                a0 += __shfl_xor(a0, 1, 64); a0 += __shfl_xor(a0, 2, 64); a0 += __shfl_xor(a0, 4, 64);
                a1 += __shfl_xor(a1, 1, 64); a1 += __shfl_xor(a1, 2, 64); a1 += __shfl_xor(a1, 4, 64);
                if (k4 == 0) {
                    last0 = a0; last1 = a1;
                    ast64(dst + ownW0, pt_pack(t, a0));
                    ast64(dst + ownW1, pt_pack(t, a1));
                }
            } else {
                if (k4 == 0) {
                    ast64(dst + ownW0, pt_pack(t, last0));
                    ast64(dst + ownW1, pt_pack(t, last1));
                }
            }
        };

        issueR(A0, A1, 127);
        for (int t = 127; t >= 65; t -= 2) {
            if (t - 1 >= 65) issueR(B0, B1, t - 1);
            stepB(t, A0, A1);
            if (t - 2 >= 65) issueR(A0, A1, t - 2);
            if (t - 1 >= 65) stepB(t - 1, B0, B1);
        }
    }
}

// ---------------------------------------------------------------------------
// Kernel 4: finalize. Q_64 = ptF parity0 (tag 64); R_64 = ptB parity1 (tag 65).
// z_b = 4*cnt_b + log( sum_{a,b} Q_64[a,b] * R_64[a,b] ).
// ---------------------------------------------------------------------------
__global__ __launch_bounds__(1024) void finalize_dfb(const float* __restrict__ ws,
                                                     const u64*  __restrict__ ptF,
                                                     const u64*  __restrict__ ptB,
                                                     const int*  __restrict__ mask,
                                                     float*      __restrict__ out) {
    __shared__ float zs[32];
    const int w = threadIdx.x >> 6, lane = threadIdx.x & 63;
    for (int rep = 0; rep < 2; ++rep) {
        const int b = w + rep * 16;
        const u64* qf = ptF + (size_t)b * 2048;          // parity0
        const u64* rb = ptB + (size_t)b * 2048 + 1024;   // parity1
        float dot = 0.f;
        #pragma unroll
        for (int e = 0; e < 16; ++e) {
            const int x = lane + 64 * e;                 // x = b*32 + a
            dot += pt_val(qf[x]) * pt_val(rb[(x & 31) * 32 + (x >> 5)]);
        }
        float cnt = 0.f;
        {
            int t = 2 + lane;
            if (t < SEQ_LEN) cnt += (mask[t*BATCH + b] != 0) ? 1.f : 0.f;
            t += 64;
            if (t < SEQ_LEN) cnt += (mask[t*BATCH + b] != 0) ? 1.f : 0.f;
        }
        #pragma unroll
        for (int off = 32; off > 0; off >>= 1) {
            dot += __shfl_xor(dot, off, 64);
            cnt += __shfl_xor(cnt, off, 64);
        }
        if (lane == 0) zs[b] = 4.0f * cnt + logf(dot);
    }
    __syncthreads();
    if (threadIdx.x == 0) {
        float tg = 0.f, z = 0.f;
        #pragma unroll
        for (int i = 0; i < 16; ++i) tg += ws[i];
        #pragma unroll
        for (int i = 0; i < 32; ++i) z += zs[i];
        out[0] = (z - tg) / (float)BATCH;
    }
}

// ---------------------------------------------------------------------------
// Fallback (small ws): round-5 single-block-per-batch scan.
// ---------------------------------------------------------------------------
__global__ __launch_bounds__(1024) void scan_fast(const float* __restrict__ scores,
                                                  const int*   __restrict__ maskI,
                                                  float*       __restrict__ ws) {
    const int b    = blockIdx.x;
    const int tid  = threadIdx.x;
    const int w    = tid >> 6;
    const int lane = tid & 63;
    const int h    = lane >> 4;
    const int jp   = (lane >> 3) & 1;
    const int k4   = lane & 7;
    const int j    = w * 2 + jp;

    __shared__ float Q[2][TT];
    __shared__ int   lmask[SEQ_LEN];
    if (tid < SEQ_LEN) lmask[tid] = maskI[tid * BATCH + b];
    {
        int x = tid >> 5, y = tid & 31;
        float p1 = scores[(size_t)(0*BATCH + b)*TTT + START*TT + START*T + x];
        float s1 = scores[(size_t)(1*BATCH + b)*TTT + START*TT + x*T + y];
        Q[1][x*T + y] = __expf(p1 + s1);
    }
    __syncthreads();
    const int loff = h*8*TT + j*T + k4*4;
    float4 SA[8], SB[8];
    auto issue = [&](float4 (&S)[8], int t) {
        const float* p = scores + ((size_t)t*BATCH + b)*TTT + loff;
        #pragma unroll
        for (int m = 0; m < 8; ++m) S[m] = *(const float4*)(p + m*TT);
    };
    auto process = [&](float4 (&S)[8], int t) {
        const float* qc = Q[(t-1) & 1];
        float*       qn = Q[t & 1];
        #pragma unroll
        for (int m = 0; m < 8; ++m) {
            S[m].x = exp2f(fmaf(S[m].x, LOG2E, -OFF4));
            S[m].y = exp2f(fmaf(S[m].y, LOG2E, -OFF4));
            S[m].z = exp2f(fmaf(S[m].z, LOG2E, -OFF4));
            S[m].w = exp2f(fmaf(S[m].w, LOG2E, -OFF4));
        }
        float4 acc = make_float4(0.f, 0.f, 0.f, 0.f);
        #pragma unroll
        for (int m = 0; m < 8; ++m) {
            float q = qc[(h*8 + m)*T + j];
            acc.x = fmaf(S[m].x, q, acc.x);
            acc.y = fmaf(S[m].y, q, acc.y);
            acc.z = fmaf(S[m].z, q, acc.z);
            acc.w = fmaf(S[m].w, q, acc.w);
        }
        acc.x += __shfl_xor(acc.x, 16, 64); acc.y += __shfl_xor(acc.y, 16, 64);
        acc.z += __shfl_xor(acc.z, 16, 64); acc.w += __shfl_xor(acc.w, 16, 64);
        acc.x += __shfl_xor(acc.x, 32, 64); acc.y += __shfl_xor(acc.y, 32, 64);
        acc.z += __shfl_xor(acc.z, 32, 64); acc.w += __shfl_xor(acc.w, 32, 64);
        if (lane < 16) {
            if (lmask[t] != 0) *(float4*)&qn[j*T + k4*4] = acc;
            else               *(float4*)&qn[j*T + k4*4] = *(const float4*)&qc[j*T + k4*4];
        }
        asm volatile("s_waitcnt lgkmcnt(0)" ::: "memory");
        __builtin_amdgcn_s_barrier();
    };
    issue(SA, 2);
    for (int t = 2; t < SEQ_LEN; t += 2) {
        issue(SB, t + 1);
        process(SA, t);
        if (t + 2 < SEQ_LEN) issue(SA, t + 2);
        process(SB, t + 1);
    }
    if (tid == 0) {
        int cnt = 0;
        for (int t = 2; t < SEQ_LEN; ++t) cnt += (lmask[t] != 0);
        ws[16 + b] = 4.0f * (float)cnt + logf(Q[1][END*T + END]);
    }
}

__global__ void finalize_simple(const float* __restrict__ ws, float* __restrict__ out) {
    if (threadIdx.x == 0) {
        float tg = 0.f, z = 0.f;
        #pragma unroll
        for (int i = 0; i < 16; ++i) tg += ws[i];
        #pragma unroll
        for (int i = 0; i < 32; ++i) z += ws[16 + i];
        out[0] = (z - tg) / (float)BATCH;
    }
}

extern "C" void kernel_launch(void* const* d_in, const int* in_sizes, int n_in,
                              void* d_out, int out_size, void* d_ws, size_t ws_size,
                              hipStream_t stream) {
    const float* scores = (const float*)d_in[0];
    const int*   target = (const int*)d_in[1];
    const int*   mask   = (const int*)d_in[2];
    float* out = (float*)d_out;
    float* ws  = (float*)d_ws;
    u64*   ptF = (u64*)((char*)d_ws + 1024);
    u64*   ptB = ptF + (size_t)BATCH * 2048;
    const size_t need = 1024 + (size_t)2 * BATCH * 2048 * sizeof(u64);   // ~1.05 MB

    tg_kernel<<<16, 256, 0, stream>>>(scores, target, mask, ws);
    if (ws_size >= need) {
        init_dfb<<<2*BATCH, 256, 0, stream>>>(scores, ptF, ptB);
        scan_rd<<<512, 512, 0, stream>>>(scores, mask, ptF, ptB);
        finalize_dfb<<<1, 1024, 0, stream>>>(ws, ptF, ptB, mask, out);
    } else {
        scan_fast<<<BATCH, 1024, 0, stream>>>(scores, mask, ws);
        finalize_simple<<<1, 64, 0, stream>>>(ws, out);
    }
}